// Round 3
// baseline (338.085 us; speedup 1.0000x reference)
//
#include <hip/hip_runtime.h>
#include <math.h>

// ---------------- problem constants ----------------
#define BATCH 16
#define IH 384
#define IW 512
#define C1 10
#define P1H 191   // pooled H after conv1(382) / 2
#define P1W 255   // pooled W after conv1(510) / 2
#define C2 16
#define H2 189
#define W2 253
#define C3 32
#define H3 187
#define W3 251
#define N3 (H3*W3)        // 46937
#define KP 128
#define CAP 7680          // max candidates kept for NMS (LDS-resident)
#define NEGV (-1e30f)

// ------------- kernel 1: conv1(3->10,3x3) + PReLU + maxpool2 -------------
__global__ __launch_bounds__(256, 2) void k_conv1pool(
        const float* __restrict__ im, const float* __restrict__ w,
        const float* __restrict__ bia, const float* __restrict__ slope,
        float* __restrict__ outp) {
    int x = blockIdx.x * 16 + threadIdx.x;
    int y = blockIdx.y * 16 + threadIdx.y;
    int bb = blockIdx.z;
    if (x >= P1W || y >= P1H) return;

    float in[3][4][4];
    #pragma unroll
    for (int ci = 0; ci < 3; ++ci) {
        const float* p = im + (((size_t)bb * 3 + ci) * IH + 2 * y) * IW + 2 * x;
        #pragma unroll
        for (int r = 0; r < 4; ++r) {
            const float2* q = (const float2*)(p + (size_t)r * IW);  // 8B-aligned
            float2 a0 = q[0], a1 = q[1];
            in[ci][r][0] = a0.x; in[ci][r][1] = a0.y;
            in[ci][r][2] = a1.x; in[ci][r][3] = a1.y;
        }
    }
    #pragma unroll
    for (int ci = 0; ci < 3; ++ci)
        #pragma unroll
        for (int r = 0; r < 4; ++r)
            #pragma unroll
            for (int c = 0; c < 4; ++c)
                in[ci][r][c] = (in[ci][r][c] - 127.5f) * 0.0078125f;

    #pragma unroll
    for (int oc = 0; oc < C1; ++oc) {
        const float* wo = w + oc * 27;  // uniform -> scalar loads
        float bv = bia[oc], sv = slope[oc];
        float best = -INFINITY;
        #pragma unroll
        for (int py = 0; py < 2; ++py)
            #pragma unroll
            for (int px = 0; px < 2; ++px) {
                float acc = bv;
                #pragma unroll
                for (int ci = 0; ci < 3; ++ci)
                    #pragma unroll
                    for (int ky = 0; ky < 3; ++ky)
                        #pragma unroll
                        for (int kx = 0; kx < 3; ++kx)
                            acc += in[ci][py + ky][px + kx] * wo[(ci * 3 + ky) * 3 + kx];
                float v = acc > 0.f ? acc : sv * acc;   // PReLU then pool-max
                best = fmaxf(best, v);
            }
        outp[(((size_t)bb * C1 + oc) * P1H + y) * P1W + x] = best;
    }
}

// ------------- kernel 2: conv2(10->16,3x3) + PReLU -------------
// 2 x-adjacent pixels x 16 oc per thread; software-pipelined input window
// (loads for ci+1 in flight during the 288-FMA block of ci) to cover the
// ~200-400cyc global-load latency that held VALUBusy at ~56%.
__global__ __launch_bounds__(256, 2) void k_conv2(
        const float* __restrict__ inp, const float* __restrict__ w,
        const float* __restrict__ bia, const float* __restrict__ slope,
        float* __restrict__ outp) {
    int x0 = (blockIdx.x * 64 + threadIdx.x) * 2;
    int y  = blockIdx.y * 4 + threadIdx.y;
    int bb = blockIdx.z;
    if (x0 >= W2 || y >= H2) return;

    float a0[C2], a1[C2];
    #pragma unroll
    for (int oc = 0; oc < C2; ++oc) { a0[oc] = bia[oc]; a1[oc] = bia[oc]; }

    bool tail = (x0 + 3 > P1W - 1);
    const float* pbase = inp + ((size_t)bb * C1 * P1H + y) * P1W + x0;
    const size_t CHS = (size_t)P1H * P1W;

    float va[3][4], vb[3][4];

    #define LOADW2(dst, ci_) { \
        const float* p = pbase + (size_t)(ci_) * CHS; \
        _Pragma("unroll") \
        for (int r = 0; r < 3; ++r) { \
            const float* pr = p + (size_t)r * P1W; \
            dst[r][0] = pr[0]; dst[r][1] = pr[1]; dst[r][2] = pr[2]; \
            dst[r][3] = tail ? 0.f : pr[3]; \
        } }

    #define ACC2(v, ci_) { \
        const float* wc = w + (ci_) * 9; \
        _Pragma("unroll") \
        for (int oc = 0; oc < C2; ++oc) { \
            const float* wo = wc + oc * (C1 * 9); \
            float s0 = a0[oc], s1 = a1[oc]; \
            _Pragma("unroll") \
            for (int ky = 0; ky < 3; ++ky) \
                _Pragma("unroll") \
                for (int kx = 0; kx < 3; ++kx) { \
                    float wv = wo[ky * 3 + kx]; \
                    s0 += v[ky][kx]     * wv; \
                    s1 += v[ky][kx + 1] * wv; \
                } \
            a0[oc] = s0; a1[oc] = s1; \
        } }

    LOADW2(va, 0);
    for (int ci = 0; ci < C1; ci += 2) {   // C1=10, even
        LOADW2(vb, ci + 1);
        ACC2(va, ci);
        if (ci + 2 < C1) LOADW2(va, ci + 2);
        ACC2(vb, ci + 1);
    }
    #undef LOADW2
    #undef ACC2

    bool px1 = (x0 + 1 < W2);
    #pragma unroll
    for (int oc = 0; oc < C2; ++oc) {
        float sl = slope[oc];
        float* o = outp + (((size_t)bb * C2 + oc) * H2 + y) * W2 + x0;
        float u0 = a0[oc]; o[0] = u0 > 0.f ? u0 : sl * u0;
        if (px1) { float u1 = a1[oc]; o[1] = u1 > 0.f ? u1 : sl * u1; }
    }
}

// ------------- kernel 3: conv3(16->32,3x3)+PReLU + heads + softmax + mask ----
// 2 x-adjacent pixels x 32 oc = 64 accumulators; same prefetch pipeline:
// window for ci+1 loads during the 576-FMA block of ci.
__global__ __launch_bounds__(256, 2) void k_conv3heads(
        const float* __restrict__ inp, const float* __restrict__ w3,
        const float* __restrict__ b3, const float* __restrict__ s3,
        const float* __restrict__ w41, const float* __restrict__ b41,
        const float* __restrict__ w42, const float* __restrict__ b42,
        float* __restrict__ scores, float4* __restrict__ regf) {
    int x0 = (blockIdx.x * 64 + threadIdx.x) * 2;
    int y  = blockIdx.y * 4 + threadIdx.y;
    int bb = blockIdx.z;
    if (x0 >= W3 || y >= H3) return;

    float a0[C3], a1[C3];
    #pragma unroll
    for (int oc = 0; oc < C3; ++oc) { a0[oc] = b3[oc]; a1[oc] = b3[oc]; }

    bool tail = (x0 + 3 > W2 - 1);
    const float* pbase = inp + ((size_t)bb * C2 * H2 + y) * W2 + x0;
    const size_t CHS = (size_t)H2 * W2;

    float va[3][4], vb[3][4];

    #define LOADW3(dst, ci_) { \
        const float* p = pbase + (size_t)(ci_) * CHS; \
        _Pragma("unroll") \
        for (int r = 0; r < 3; ++r) { \
            const float* pr = p + (size_t)r * W2; \
            dst[r][0] = pr[0]; dst[r][1] = pr[1]; dst[r][2] = pr[2]; \
            dst[r][3] = tail ? 0.f : pr[3]; \
        } }

    #define ACC3(v, ci_) { \
        const float* wc = w3 + (ci_) * 9; \
        _Pragma("unroll") \
        for (int oc = 0; oc < C3; ++oc) { \
            const float* wo = wc + oc * (C2 * 9); \
            float s0 = a0[oc], s1 = a1[oc]; \
            _Pragma("unroll") \
            for (int ky = 0; ky < 3; ++ky) \
                _Pragma("unroll") \
                for (int kx = 0; kx < 3; ++kx) { \
                    float wv = wo[ky * 3 + kx]; \
                    s0 += v[ky][kx]     * wv; \
                    s1 += v[ky][kx + 1] * wv; \
                } \
            a0[oc] = s0; a1[oc] = s1; \
        } }

    LOADW3(va, 0);
    for (int ci = 0; ci < C2; ci += 2) {   // C2=16, even
        LOADW3(vb, ci + 1);
        ACC3(va, ci);
        if (ci + 2 < C2) LOADW3(va, ci + 2);
        ACC3(vb, ci + 1);
    }
    #undef LOADW3
    #undef ACC3

    #pragma unroll
    for (int oc = 0; oc < C3; ++oc) {
        float u0 = a0[oc], u1 = a1[oc], sl = s3[oc];
        a0[oc] = u0 > 0.f ? u0 : sl * u0;
        a1[oc] = u1 > 0.f ? u1 : sl * u1;
    }

    // ---- heads (both pixels) ----
    float l00 = b41[0], l01 = b41[1], l10 = b41[0], l11 = b41[1];
    #pragma unroll
    for (int c = 0; c < C3; ++c) {
        float w0 = w41[c], w1 = w41[C3 + c];
        l00 += a0[c] * w0; l01 += a0[c] * w1;
        l10 += a1[c] * w0; l11 += a1[c] * w1;
    }
    float m0 = fmaxf(l00, l01), m1 = fmaxf(l10, l11);
    float p0 = expf(l01 - m0) / (expf(l00 - m0) + expf(l01 - m0));
    float p1 = expf(l11 - m1) / (expf(l10 - m1) + expf(l11 - m1));

    float r00 = b42[0], r01 = b42[1], r02 = b42[2], r03 = b42[3];
    float r10 = b42[0], r11 = b42[1], r12 = b42[2], r13 = b42[3];
    #pragma unroll
    for (int c = 0; c < C3; ++c) {
        float w0 = w42[c], w1 = w42[C3 + c], w2 = w42[2 * C3 + c], w3v = w42[3 * C3 + c];
        r00 += a0[c] * w0; r01 += a0[c] * w1; r02 += a0[c] * w2; r03 += a0[c] * w3v;
        r10 += a1[c] * w0; r11 += a1[c] * w1; r12 += a1[c] * w2; r13 += a1[c] * w3v;
    }

    size_t n0 = (size_t)bb * N3 + y * W3 + x0;
    scores[n0] = (p0 >= 0.6f) ? p0 : NEGV;
    regf[n0]   = make_float4(r00, r01, r02, r03);
    if (x0 + 1 < W3) {
        scores[n0 + 1] = (p1 >= 0.6f) ? p1 : NEGV;
        regf[n0 + 1]   = make_float4(r10, r11, r12, r13);
    }
}

// ------------- kernel 4: per-image NMS (LDS-resident) + box refine -------------
__global__ __launch_bounds__(1024) void k_nms(
        const float* __restrict__ scores, const float4* __restrict__ regf,
        float* __restrict__ outp) {
    __shared__ float s_score[CAP];
    __shared__ int   s_idx[CAP];     // also reused as 2048-bin histogram
    __shared__ float r_s[16];
    __shared__ int   r_i[16];
    __shared__ float s_picks[KP];
    __shared__ int   s_picki[KP];
    __shared__ int   s_misc[4];

    int tid = threadIdx.x;
    int bb = blockIdx.x;
    const float* sc = scores + (size_t)bb * N3;

    if (tid < 4) s_misc[tid] = 0;
    __syncthreads();

    int cnt = 0;
    for (int i = tid; i < N3; i += 1024) if (sc[i] > 0.f) cnt++;
    atomicAdd(&s_misc[0], cnt);
    __syncthreads();
    int M = s_misc[0];

    int cutbin = 0;
    if (M > CAP) {
        for (int i = tid; i < 2048; i += 1024) s_idx[i] = 0;
        __syncthreads();
        for (int i = tid; i < N3; i += 1024) {
            float s = sc[i];
            if (s > 0.f) {
                int b = (int)((s - 0.6f) * 5120.f);
                b = b < 0 ? 0 : (b > 2047 ? 2047 : b);
                atomicAdd(&s_idx[b], 1);
            }
        }
        __syncthreads();
        if (tid == 0) {
            int accum = 0, b = 2047;
            for (; b >= 0; --b) {
                int c = s_idx[b];
                if (accum + c > CAP) break;
                accum += c;
            }
            s_misc[2] = b + 1;
        }
        __syncthreads();
        cutbin = s_misc[2];
        __syncthreads();
    }

    for (int i = tid; i < N3; i += 1024) {
        float s = sc[i];
        if (s > 0.f) {
            bool keep = true;
            if (M > CAP) {
                int b = (int)((s - 0.6f) * 5120.f);
                b = b < 0 ? 0 : (b > 2047 ? 2047 : b);
                keep = (b >= cutbin);
            }
            if (keep) {
                int pos = atomicAdd(&s_misc[1], 1);
                if (pos < CAP) { s_score[pos] = s; s_idx[pos] = i; }
            }
        }
    }
    __syncthreads();
    int M2 = s_misc[1]; if (M2 > CAP) M2 = CAP;

    int np = 0;
    for (int pick = 0; pick < KP; ++pick) {
        float bs = -INFINITY; int bi = 0x7fffffff;
        for (int i = tid; i < M2; i += 1024) {
            float s = s_score[i]; int id = s_idx[i];
            if (s > bs || (s == bs && id < bi)) { bs = s; bi = id; }
        }
        #pragma unroll
        for (int off = 32; off; off >>= 1) {
            float os = __shfl_down(bs, off);
            int   oi = __shfl_down(bi, off);
            if (os > bs || (os == bs && oi < bi)) { bs = os; bi = oi; }
        }
        int lane = tid & 63, wv = tid >> 6;
        if (lane == 0) { r_s[wv] = bs; r_i[wv] = bi; }
        __syncthreads();
        if (tid == 0) {
            float ps = r_s[0]; int pi = r_i[0];
            for (int k = 1; k < 16; ++k) {
                float os = r_s[k]; int oi = r_i[k];
                if (os > ps || (os == ps && oi < pi)) { ps = os; pi = oi; }
            }
            s_picks[pick] = ps; s_picki[pick] = pi;
            r_s[0] = ps; r_i[0] = pi;
        }
        __syncthreads();
        float ps = r_s[0]; int pi = r_i[0];
        if (ps < 0.f) break;
        np = pick + 1;

        int pcx = pi % W3, pcy = pi / W3;
        float px1 = (float)(2 * pcx + 1), py1 = (float)(2 * pcy + 1);
        float px2 = (float)(2 * pcx + 12), py2 = (float)(2 * pcy + 12);
        for (int i = tid; i < M2; i += 1024) {
            float s = s_score[i];
            if (s > NEGV * 0.5f) {
                int id = s_idx[i];
                int cx = id % W3, cy = id / W3;
                float x1 = (float)(2 * cx + 1), y1 = (float)(2 * cy + 1);
                float x2 = (float)(2 * cx + 12), y2 = (float)(2 * cy + 12);
                float xx1 = fmaxf(px1, x1), yy1 = fmaxf(py1, y1);
                float xx2 = fminf(px2, x2), yy2 = fminf(py2, y2);
                float inter = fmaxf(0.f, xx2 - xx1 + 1.f) * fmaxf(0.f, yy2 - yy1 + 1.f);
                float iou = inter / (288.f - inter);
                if (iou > 0.5f) s_score[i] = NEGV;
            }
        }
        __syncthreads();
    }

    if (tid < KP) {
        float* o = outp + ((size_t)bb * KP + tid) * 5;
        if (tid < np) {
            int pi = s_picki[tid]; float ps = s_picks[tid];
            int cx = pi % W3, cy = pi / W3;
            float x1 = (float)(2 * cx + 1), y1 = (float)(2 * cy + 1);
            float x2 = (float)(2 * cx + 12), y2 = (float)(2 * cy + 12);
            float4 r = regf[(size_t)bb * N3 + pi];
            float wd = x2 - x1, hh = y2 - y1;
            float q1 = x1 + r.x * wd, q2 = y1 + r.y * hh;
            float q3 = x2 + r.z * wd, q4 = y2 + r.w * hh;
            float rw = q3 - q1, rh = q4 - q2;
            float L = fmaxf(rw, rh);
            float nx1 = q1 + rw * 0.5f - L * 0.5f;
            float ny1 = q2 + rh * 0.5f - L * 0.5f;
            o[0] = nx1; o[1] = ny1; o[2] = nx1 + L; o[3] = ny1 + L; o[4] = ps;
        } else {
            o[0] = 0.f; o[1] = 0.f; o[2] = 0.f; o[3] = 0.f; o[4] = 0.f;
        }
    }
}

// ---------------- launcher ----------------
extern "C" void kernel_launch(void* const* d_in, const int* in_sizes, int n_in,
                              void* d_out, int out_size, void* d_ws, size_t ws_size,
                              hipStream_t stream) {
    const float* im   = (const float*)d_in[0];
    const float* c1w  = (const float*)d_in[1];
    const float* c1b  = (const float*)d_in[2];
    const float* p1   = (const float*)d_in[3];
    const float* c2w  = (const float*)d_in[4];
    const float* c2b  = (const float*)d_in[5];
    const float* p2   = (const float*)d_in[6];
    const float* c3w  = (const float*)d_in[7];
    const float* c3b  = (const float*)d_in[8];
    const float* p3   = (const float*)d_in[9];
    const float* c41w = (const float*)d_in[10];
    const float* c41b = (const float*)d_in[11];
    const float* c42w = (const float*)d_in[12];
    const float* c42b = (const float*)d_in[13];

    float* ws = (float*)d_ws;
    const size_t POOL1_FLOATS = (size_t)BATCH * C1 * P1H * P1W;   // 7,792,800
    float*  pool1  = ws;
    float*  conv2b = ws + POOL1_FLOATS;
    float*  scoresb = ws;                                        // reuse region0
    float4* regfb   = (float4*)(ws + (size_t)BATCH * N3);        // 16B-aligned

    k_conv1pool<<<dim3(16, 12, BATCH), dim3(16, 16), 0, stream>>>(im, c1w, c1b, p1, pool1);
    k_conv2   <<<dim3(2, 48, BATCH), dim3(64, 4), 0, stream>>>(pool1, c2w, c2b, p2, conv2b);
    k_conv3heads<<<dim3(2, 47, BATCH), dim3(64, 4), 0, stream>>>(conv2b, c3w, c3b, p3,
                                                                 c41w, c41b, c42w, c42b,
                                                                 scoresb, regfb);
    k_nms<<<dim3(BATCH), dim3(1024), 0, stream>>>(scoresb, regfb, (float*)d_out);
}

// Round 4
// 320.985 us; speedup vs baseline: 1.0533x; 1.0533x over previous
//
#include <hip/hip_runtime.h>
#include <math.h>

// ---------------- problem constants ----------------
#define BATCH 16
#define IH 384
#define IW 512
#define C1 10
#define P1H 191   // pooled H after conv1(382) / 2
#define P1W 255   // pooled W after conv1(510) / 2
#define C2 16
#define H2 189
#define W2 253
#define C3 32
#define H3 187
#define W3 251
#define N3 (H3*W3)        // 46937
#define KP 128
#define CAP 7680          // max candidates kept for NMS (LDS-resident)
#define NEGV (-1e30f)

// ------------- kernel 1: conv1(3->10,3x3) + PReLU + maxpool2 -------------
__global__ __launch_bounds__(256, 2) void k_conv1pool(
        const float* __restrict__ im, const float* __restrict__ w,
        const float* __restrict__ bia, const float* __restrict__ slope,
        float* __restrict__ outp) {
    int x = blockIdx.x * 16 + threadIdx.x;
    int y = blockIdx.y * 16 + threadIdx.y;
    int bb = blockIdx.z;
    if (x >= P1W || y >= P1H) return;

    float in[3][4][4];
    #pragma unroll
    for (int ci = 0; ci < 3; ++ci) {
        const float* p = im + (((size_t)bb * 3 + ci) * IH + 2 * y) * IW + 2 * x;
        #pragma unroll
        for (int r = 0; r < 4; ++r) {
            const float2* q = (const float2*)(p + (size_t)r * IW);  // 8B-aligned
            float2 a0 = q[0], a1 = q[1];
            in[ci][r][0] = a0.x; in[ci][r][1] = a0.y;
            in[ci][r][2] = a1.x; in[ci][r][3] = a1.y;
        }
    }
    #pragma unroll
    for (int ci = 0; ci < 3; ++ci)
        #pragma unroll
        for (int r = 0; r < 4; ++r)
            #pragma unroll
            for (int c = 0; c < 4; ++c)
                in[ci][r][c] = (in[ci][r][c] - 127.5f) * 0.0078125f;

    #pragma unroll
    for (int oc = 0; oc < C1; ++oc) {
        const float* wo = w + oc * 27;  // uniform -> scalar loads
        float bv = bia[oc], sv = slope[oc];
        float best = -INFINITY;
        #pragma unroll
        for (int py = 0; py < 2; ++py)
            #pragma unroll
            for (int px = 0; px < 2; ++px) {
                float acc = bv;
                #pragma unroll
                for (int ci = 0; ci < 3; ++ci)
                    #pragma unroll
                    for (int ky = 0; ky < 3; ++ky)
                        #pragma unroll
                        for (int kx = 0; kx < 3; ++kx)
                            acc += in[ci][py + ky][px + kx] * wo[(ci * 3 + ky) * 3 + kx];
                float v = acc > 0.f ? acc : sv * acc;   // PReLU then pool-max
                best = fmaxf(best, v);
            }
        outp[(((size_t)bb * C1 + oc) * P1H + y) * P1W + x] = best;
    }
}

// ------------- kernel 2: conv2(10->16,3x3) + PReLU -------------
// R1 structure (2 x-adjacent pixels x 16 oc); no hand pipelining (R2 showed
// the explicit double-buffer bloats VGPR and adds shuffle VALU work).
__global__ __launch_bounds__(256, 2) void k_conv2(
        const float* __restrict__ inp, const float* __restrict__ w,
        const float* __restrict__ bia, const float* __restrict__ slope,
        float* __restrict__ outp) {
    int x0 = (blockIdx.x * 64 + threadIdx.x) * 2;
    int y  = blockIdx.y * 4 + threadIdx.y;
    int bb = blockIdx.z;
    if (x0 >= W2 || y >= H2) return;

    float a0[C2], a1[C2];
    #pragma unroll
    for (int oc = 0; oc < C2; ++oc) { a0[oc] = bia[oc]; a1[oc] = bia[oc]; }

    bool tail = (x0 + 3 > P1W - 1);

    for (int ci = 0; ci < C1; ++ci) {
        const float* p = inp + (((size_t)bb * C1 + ci) * P1H + y) * P1W + x0;
        float v[3][4];
        #pragma unroll
        for (int r = 0; r < 3; ++r) {
            const float* pr = p + (size_t)r * P1W;
            v[r][0] = pr[0]; v[r][1] = pr[1]; v[r][2] = pr[2];
            v[r][3] = tail ? 0.f : pr[3];
        }
        const float* wc = w + ci * 9;
        #pragma unroll
        for (int oc = 0; oc < C2; ++oc) {
            const float* wo = wc + oc * (C1 * 9);
            float s0 = a0[oc], s1 = a1[oc];
            #pragma unroll
            for (int ky = 0; ky < 3; ++ky)
                #pragma unroll
                for (int kx = 0; kx < 3; ++kx) {
                    float wv = wo[ky * 3 + kx];
                    s0 += v[ky][kx]     * wv;
                    s1 += v[ky][kx + 1] * wv;
                }
            a0[oc] = s0; a1[oc] = s1;
        }
    }
    bool px1 = (x0 + 1 < W2);
    #pragma unroll
    for (int oc = 0; oc < C2; ++oc) {
        float sl = slope[oc];
        float* o = outp + (((size_t)bb * C2 + oc) * H2 + y) * W2 + x0;
        float u0 = a0[oc]; o[0] = u0 > 0.f ? u0 : sl * u0;
        if (px1) { float u1 = a1[oc]; o[1] = u1 > 0.f ? u1 : sl * u1; }
    }
}

// ------------- kernel 3: conv3(16->32,3x3)+PReLU + heads + softmax + mask ----
// 2x2 pixel block x all 32 oc per thread: 1152 FMAs per ci for the same 288
// uniform weight dwords (2x the weight amortization of the 2-px version) and
// 16 window loads for 4 pixels. 128 accumulators -> ~170 VGPR -> 3 waves/SIMD,
// matching the 3 blocks/CU the grid provides.
__global__ __launch_bounds__(256, 2) void k_conv3heads(
        const float* __restrict__ inp, const float* __restrict__ w3,
        const float* __restrict__ b3, const float* __restrict__ s3,
        const float* __restrict__ w41, const float* __restrict__ b41,
        const float* __restrict__ w42, const float* __restrict__ b42,
        float* __restrict__ scores, float4* __restrict__ regf) {
    int x0 = (blockIdx.x * 64 + threadIdx.x) * 2;   // even, 0..254
    int y0 = (blockIdx.y * 4 + threadIdx.y) * 2;    // even, 0..190
    int bb = blockIdx.z;
    if (x0 >= W3 || y0 >= H3) return;

    float a00[C3], a01[C3], a10[C3], a11[C3];
    #pragma unroll
    for (int oc = 0; oc < C3; ++oc) {
        float bv = b3[oc];
        a00[oc] = bv; a01[oc] = bv; a10[oc] = bv; a11[oc] = bv;
    }

    // col 3 of the 4-wide window exceeds W2-1 only at x0==250;
    // row 3 of the 4-tall window exceeds H2-1 only at y0==186.
    bool ctail = (x0 + 3 > W2 - 1);
    bool rtail = (y0 + 3 > H2 - 1);

    for (int ci = 0; ci < C2; ++ci) {
        const float* p = inp + (((size_t)bb * C2 + ci) * H2 + y0) * W2 + x0;
        float v[4][4];
        #pragma unroll
        for (int r = 0; r < 4; ++r) {
            bool rv = (r < 3) || !rtail;
            const float* pr = p + (size_t)r * W2;
            v[r][0] = rv ? pr[0] : 0.f;
            v[r][1] = rv ? pr[1] : 0.f;
            v[r][2] = rv ? pr[2] : 0.f;
            v[r][3] = (rv && !ctail) ? pr[3] : 0.f;
        }
        #pragma unroll
        for (int oc = 0; oc < C3; ++oc) {
            const float* wo = w3 + (oc * C2 + ci) * 9;
            float s00 = a00[oc], s01 = a01[oc], s10 = a10[oc], s11 = a11[oc];
            #pragma unroll
            for (int ky = 0; ky < 3; ++ky)
                #pragma unroll
                for (int kx = 0; kx < 3; ++kx) {
                    float wv = wo[ky * 3 + kx];
                    s00 += v[ky][kx]         * wv;
                    s01 += v[ky][kx + 1]     * wv;
                    s10 += v[ky + 1][kx]     * wv;
                    s11 += v[ky + 1][kx + 1] * wv;
                }
            a00[oc] = s00; a01[oc] = s01; a10[oc] = s10; a11[oc] = s11;
        }
    }

    #pragma unroll
    for (int oc = 0; oc < C3; ++oc) {
        float sl = s3[oc];
        float u;
        u = a00[oc]; a00[oc] = u > 0.f ? u : sl * u;
        u = a01[oc]; a01[oc] = u > 0.f ? u : sl * u;
        u = a10[oc]; a10[oc] = u > 0.f ? u : sl * u;
        u = a11[oc]; a11[oc] = u > 0.f ? u : sl * u;
    }

    bool px1 = (x0 + 1 < W3);
    bool py1 = (y0 + 1 < H3);

    #define HEADS(A, yy, xx, valid) { \
        if (valid) { \
            float l0 = b41[0], l1 = b41[1]; \
            _Pragma("unroll") \
            for (int c = 0; c < C3; ++c) { l0 += A[c] * w41[c]; l1 += A[c] * w41[C3 + c]; } \
            float m = fmaxf(l0, l1); \
            float e0 = expf(l0 - m), e1 = expf(l1 - m); \
            float pv = e1 / (e0 + e1); \
            float r0 = b42[0], r1 = b42[1], r2 = b42[2], r3v = b42[3]; \
            _Pragma("unroll") \
            for (int c = 0; c < C3; ++c) { \
                r0 += A[c] * w42[c];          r1 += A[c] * w42[C3 + c]; \
                r2 += A[c] * w42[2 * C3 + c]; r3v += A[c] * w42[3 * C3 + c]; \
            } \
            size_t n = (size_t)bb * N3 + (size_t)(yy) * W3 + (xx); \
            scores[n] = (pv >= 0.6f) ? pv : NEGV; \
            regf[n]   = make_float4(r0, r1, r2, r3v); \
        } }

    HEADS(a00, y0,     x0,     true)
    HEADS(a01, y0,     x0 + 1, px1)
    HEADS(a10, y0 + 1, x0,     py1)
    HEADS(a11, y0 + 1, x0 + 1, px1 && py1)
    #undef HEADS
}

// ------------- kernel 4: per-image NMS (LDS-resident) + box refine -------------
__global__ __launch_bounds__(1024) void k_nms(
        const float* __restrict__ scores, const float4* __restrict__ regf,
        float* __restrict__ outp) {
    __shared__ float s_score[CAP];
    __shared__ int   s_idx[CAP];     // also reused as 2048-bin histogram
    __shared__ float r_s[16];
    __shared__ int   r_i[16];
    __shared__ float s_picks[KP];
    __shared__ int   s_picki[KP];
    __shared__ int   s_misc[4];

    int tid = threadIdx.x;
    int bb = blockIdx.x;
    const float* sc = scores + (size_t)bb * N3;

    if (tid < 4) s_misc[tid] = 0;
    __syncthreads();

    int cnt = 0;
    for (int i = tid; i < N3; i += 1024) if (sc[i] > 0.f) cnt++;
    atomicAdd(&s_misc[0], cnt);
    __syncthreads();
    int M = s_misc[0];

    int cutbin = 0;
    if (M > CAP) {
        for (int i = tid; i < 2048; i += 1024) s_idx[i] = 0;
        __syncthreads();
        for (int i = tid; i < N3; i += 1024) {
            float s = sc[i];
            if (s > 0.f) {
                int b = (int)((s - 0.6f) * 5120.f);
                b = b < 0 ? 0 : (b > 2047 ? 2047 : b);
                atomicAdd(&s_idx[b], 1);
            }
        }
        __syncthreads();
        if (tid == 0) {
            int accum = 0, b = 2047;
            for (; b >= 0; --b) {
                int c = s_idx[b];
                if (accum + c > CAP) break;
                accum += c;
            }
            s_misc[2] = b + 1;
        }
        __syncthreads();
        cutbin = s_misc[2];
        __syncthreads();
    }

    for (int i = tid; i < N3; i += 1024) {
        float s = sc[i];
        if (s > 0.f) {
            bool keep = true;
            if (M > CAP) {
                int b = (int)((s - 0.6f) * 5120.f);
                b = b < 0 ? 0 : (b > 2047 ? 2047 : b);
                keep = (b >= cutbin);
            }
            if (keep) {
                int pos = atomicAdd(&s_misc[1], 1);
                if (pos < CAP) { s_score[pos] = s; s_idx[pos] = i; }
            }
        }
    }
    __syncthreads();
    int M2 = s_misc[1]; if (M2 > CAP) M2 = CAP;

    int np = 0;
    for (int pick = 0; pick < KP; ++pick) {
        float bs = -INFINITY; int bi = 0x7fffffff;
        for (int i = tid; i < M2; i += 1024) {
            float s = s_score[i]; int id = s_idx[i];
            if (s > bs || (s == bs && id < bi)) { bs = s; bi = id; }
        }
        #pragma unroll
        for (int off = 32; off; off >>= 1) {
            float os = __shfl_down(bs, off);
            int   oi = __shfl_down(bi, off);
            if (os > bs || (os == bs && oi < bi)) { bs = os; bi = oi; }
        }
        int lane = tid & 63, wv = tid >> 6;
        if (lane == 0) { r_s[wv] = bs; r_i[wv] = bi; }
        __syncthreads();
        if (tid == 0) {
            float ps = r_s[0]; int pi = r_i[0];
            for (int k = 1; k < 16; ++k) {
                float os = r_s[k]; int oi = r_i[k];
                if (os > ps || (os == ps && oi < pi)) { ps = os; pi = oi; }
            }
            s_picks[pick] = ps; s_picki[pick] = pi;
            r_s[0] = ps; r_i[0] = pi;
        }
        __syncthreads();
        float ps = r_s[0]; int pi = r_i[0];
        if (ps < 0.f) break;
        np = pick + 1;

        int pcx = pi % W3, pcy = pi / W3;
        float px1 = (float)(2 * pcx + 1), py1 = (float)(2 * pcy + 1);
        float px2 = (float)(2 * pcx + 12), py2 = (float)(2 * pcy + 12);
        for (int i = tid; i < M2; i += 1024) {
            float s = s_score[i];
            if (s > NEGV * 0.5f) {
                int id = s_idx[i];
                int cx = id % W3, cy = id / W3;
                float x1 = (float)(2 * cx + 1), y1 = (float)(2 * cy + 1);
                float x2 = (float)(2 * cx + 12), y2 = (float)(2 * cy + 12);
                float xx1 = fmaxf(px1, x1), yy1 = fmaxf(py1, y1);
                float xx2 = fminf(px2, x2), yy2 = fminf(py2, y2);
                float inter = fmaxf(0.f, xx2 - xx1 + 1.f) * fmaxf(0.f, yy2 - yy1 + 1.f);
                float iou = inter / (288.f - inter);
                if (iou > 0.5f) s_score[i] = NEGV;
            }
        }
        __syncthreads();
    }

    if (tid < KP) {
        float* o = outp + ((size_t)bb * KP + tid) * 5;
        if (tid < np) {
            int pi = s_picki[tid]; float ps = s_picks[tid];
            int cx = pi % W3, cy = pi / W3;
            float x1 = (float)(2 * cx + 1), y1 = (float)(2 * cy + 1);
            float x2 = (float)(2 * cx + 12), y2 = (float)(2 * cy + 12);
            float4 r = regf[(size_t)bb * N3 + pi];
            float wd = x2 - x1, hh = y2 - y1;
            float q1 = x1 + r.x * wd, q2 = y1 + r.y * hh;
            float q3 = x2 + r.z * wd, q4 = y2 + r.w * hh;
            float rw = q3 - q1, rh = q4 - q2;
            float L = fmaxf(rw, rh);
            float nx1 = q1 + rw * 0.5f - L * 0.5f;
            float ny1 = q2 + rh * 0.5f - L * 0.5f;
            o[0] = nx1; o[1] = ny1; o[2] = nx1 + L; o[3] = ny1 + L; o[4] = ps;
        } else {
            o[0] = 0.f; o[1] = 0.f; o[2] = 0.f; o[3] = 0.f; o[4] = 0.f;
        }
    }
}

// ---------------- launcher ----------------
extern "C" void kernel_launch(void* const* d_in, const int* in_sizes, int n_in,
                              void* d_out, int out_size, void* d_ws, size_t ws_size,
                              hipStream_t stream) {
    const float* im   = (const float*)d_in[0];
    const float* c1w  = (const float*)d_in[1];
    const float* c1b  = (const float*)d_in[2];
    const float* p1   = (const float*)d_in[3];
    const float* c2w  = (const float*)d_in[4];
    const float* c2b  = (const float*)d_in[5];
    const float* p2   = (const float*)d_in[6];
    const float* c3w  = (const float*)d_in[7];
    const float* c3b  = (const float*)d_in[8];
    const float* p3   = (const float*)d_in[9];
    const float* c41w = (const float*)d_in[10];
    const float* c41b = (const float*)d_in[11];
    const float* c42w = (const float*)d_in[12];
    const float* c42b = (const float*)d_in[13];

    float* ws = (float*)d_ws;
    const size_t POOL1_FLOATS = (size_t)BATCH * C1 * P1H * P1W;   // 7,792,800
    float*  pool1  = ws;
    float*  conv2b = ws + POOL1_FLOATS;
    float*  scoresb = ws;                                        // reuse region0
    float4* regfb   = (float4*)(ws + (size_t)BATCH * N3);        // 16B-aligned

    k_conv1pool<<<dim3(16, 12, BATCH), dim3(16, 16), 0, stream>>>(im, c1w, c1b, p1, pool1);
    k_conv2   <<<dim3(2, 48, BATCH), dim3(64, 4), 0, stream>>>(pool1, c2w, c2b, p2, conv2b);
    k_conv3heads<<<dim3(2, 24, BATCH), dim3(64, 4), 0, stream>>>(conv2b, c3w, c3b, p3,
                                                                 c41w, c41b, c42w, c42b,
                                                                 scoresb, regfb);
    k_nms<<<dim3(BATCH), dim3(1024), 0, stream>>>(scoresb, regfb, (float*)d_out);
}

// Round 5
// 294.524 us; speedup vs baseline: 1.1479x; 1.0898x over previous
//
#include <hip/hip_runtime.h>
#include <math.h>

// ---------------- problem constants ----------------
#define BATCH 16
#define IH 384
#define IW 512
#define C1 10
#define P1H 191   // pooled H after conv1(382) / 2
#define P1W 255   // pooled W after conv1(510) / 2
#define C2 16
#define H2 189
#define W2 253
#define C3 32
#define H3 187
#define W3 251
#define N3 (H3*W3)        // 46937
#define KP 128
#define NCAP 1536         // NMS kept-candidate capacity (>= 1152 rank bound)
#define NEGV (-1e30f)

// ------------- kernel 1: conv1(3->10,3x3) + PReLU + maxpool2 -------------
// 64-thread (1-wave) workgroups: one row of pooled output per block.
__global__ __launch_bounds__(64, 2) void k_conv1pool(
        const float* __restrict__ im, const float* __restrict__ w,
        const float* __restrict__ bia, const float* __restrict__ slope,
        float* __restrict__ outp) {
    int x = blockIdx.x * 64 + threadIdx.x;
    int y = blockIdx.y;
    int bb = blockIdx.z;
    if (x >= P1W) return;

    float in[3][4][4];
    #pragma unroll
    for (int ci = 0; ci < 3; ++ci) {
        const float* p = im + (((size_t)bb * 3 + ci) * IH + 2 * y) * IW + 2 * x;
        #pragma unroll
        for (int r = 0; r < 4; ++r) {
            const float2* q = (const float2*)(p + (size_t)r * IW);  // 8B-aligned
            float2 a0 = q[0], a1 = q[1];
            in[ci][r][0] = a0.x; in[ci][r][1] = a0.y;
            in[ci][r][2] = a1.x; in[ci][r][3] = a1.y;
        }
    }
    #pragma unroll
    for (int ci = 0; ci < 3; ++ci)
        #pragma unroll
        for (int r = 0; r < 4; ++r)
            #pragma unroll
            for (int c = 0; c < 4; ++c)
                in[ci][r][c] = (in[ci][r][c] - 127.5f) * 0.0078125f;

    #pragma unroll
    for (int oc = 0; oc < C1; ++oc) {
        const float* wo = w + oc * 27;  // uniform -> scalar loads
        float bv = bia[oc], sv = slope[oc];
        float best = -INFINITY;
        #pragma unroll
        for (int py = 0; py < 2; ++py)
            #pragma unroll
            for (int px = 0; px < 2; ++px) {
                float acc = bv;
                #pragma unroll
                for (int ci = 0; ci < 3; ++ci)
                    #pragma unroll
                    for (int ky = 0; ky < 3; ++ky)
                        #pragma unroll
                        for (int kx = 0; kx < 3; ++kx)
                            acc += in[ci][py + ky][px + kx] * wo[(ci * 3 + ky) * 3 + kx];
                float v = acc > 0.f ? acc : sv * acc;   // PReLU then pool-max
                best = fmaxf(best, v);
            }
        outp[(((size_t)bb * C1 + oc) * P1H + y) * P1W + x] = best;
    }
}

// ------------- kernel 2: conv2(10->16,3x3) + PReLU -------------
// proven R1 inner loop (2 px x 16 oc); 1-wave workgroups for occupancy.
__global__ __launch_bounds__(64, 2) void k_conv2(
        const float* __restrict__ inp, const float* __restrict__ w,
        const float* __restrict__ bia, const float* __restrict__ slope,
        float* __restrict__ outp) {
    int x0 = (blockIdx.x * 64 + threadIdx.x) * 2;
    int y  = blockIdx.y;
    int bb = blockIdx.z;
    if (x0 >= W2) return;

    float a0[C2], a1[C2];
    #pragma unroll
    for (int oc = 0; oc < C2; ++oc) { a0[oc] = bia[oc]; a1[oc] = bia[oc]; }

    bool tail = (x0 + 3 > P1W - 1);

    for (int ci = 0; ci < C1; ++ci) {
        const float* p = inp + (((size_t)bb * C1 + ci) * P1H + y) * P1W + x0;
        float v[3][4];
        #pragma unroll
        for (int r = 0; r < 3; ++r) {
            const float* pr = p + (size_t)r * P1W;
            v[r][0] = pr[0]; v[r][1] = pr[1]; v[r][2] = pr[2];
            v[r][3] = tail ? 0.f : pr[3];
        }
        const float* wc = w + ci * 9;
        #pragma unroll
        for (int oc = 0; oc < C2; ++oc) {
            const float* wo = wc + oc * (C1 * 9);
            float s0 = a0[oc], s1 = a1[oc];
            #pragma unroll
            for (int ky = 0; ky < 3; ++ky)
                #pragma unroll
                for (int kx = 0; kx < 3; ++kx) {
                    float wv = wo[ky * 3 + kx];
                    s0 += v[ky][kx]     * wv;
                    s1 += v[ky][kx + 1] * wv;
                }
            a0[oc] = s0; a1[oc] = s1;
        }
    }
    bool px1 = (x0 + 1 < W2);
    #pragma unroll
    for (int oc = 0; oc < C2; ++oc) {
        float sl = slope[oc];
        float* o = outp + (((size_t)bb * C2 + oc) * H2 + y) * W2 + x0;
        float u0 = a0[oc]; o[0] = u0 > 0.f ? u0 : sl * u0;
        if (px1) { float u1 = a1[oc]; o[1] = u1 > 0.f ? u1 : sl * u1; }
    }
}

// ---- tiny repack: w3 (OIHW, oc-major) -> ci-major so conv3's per-ci weight
// reads are one contiguous 288-dword run (batched s_load, fewer lgkm stalls).
__global__ void k_repack(const float* __restrict__ w3, float* __restrict__ w3t) {
    int i = blockIdx.x * 256 + threadIdx.x;
    if (i < C3 * C2 * 9) {
        int k = i % 9, r = i / 9;
        int ci = r / C3, oc = r % C3;
        w3t[i] = w3[(oc * C2 + ci) * 9 + k];
    }
}

// ------------- kernel 3: conv3(16->32,3x3)+PReLU + heads + softmax + mask ----
// proven R1 inner loop (2 px x 32 oc, 52 VGPR); 1-wave workgroups; repacked weights.
__global__ __launch_bounds__(64, 2) void k_conv3heads(
        const float* __restrict__ inp, const float* __restrict__ w3t,
        const float* __restrict__ b3, const float* __restrict__ s3,
        const float* __restrict__ w41, const float* __restrict__ b41,
        const float* __restrict__ w42, const float* __restrict__ b42,
        float* __restrict__ scores, float4* __restrict__ regf) {
    int x0 = (blockIdx.x * 64 + threadIdx.x) * 2;
    int y  = blockIdx.y;
    int bb = blockIdx.z;
    if (x0 >= W3) return;

    float a0[C3], a1[C3];
    #pragma unroll
    for (int oc = 0; oc < C3; ++oc) { a0[oc] = b3[oc]; a1[oc] = b3[oc]; }

    bool tail = (x0 + 3 > W2 - 1);

    for (int ci = 0; ci < C2; ++ci) {
        const float* p = inp + (((size_t)bb * C2 + ci) * H2 + y) * W2 + x0;
        float v[3][4];
        #pragma unroll
        for (int r = 0; r < 3; ++r) {
            const float* pr = p + (size_t)r * W2;
            v[r][0] = pr[0]; v[r][1] = pr[1]; v[r][2] = pr[2];
            v[r][3] = tail ? 0.f : pr[3];
        }
        const float* wc = w3t + ci * (C3 * 9);   // ci-major: contiguous per ci
        #pragma unroll
        for (int oc = 0; oc < C3; ++oc) {
            const float* wo = wc + oc * 9;
            float s0 = a0[oc], s1 = a1[oc];
            #pragma unroll
            for (int ky = 0; ky < 3; ++ky)
                #pragma unroll
                for (int kx = 0; kx < 3; ++kx) {
                    float wv = wo[ky * 3 + kx];
                    s0 += v[ky][kx]     * wv;
                    s1 += v[ky][kx + 1] * wv;
                }
            a0[oc] = s0; a1[oc] = s1;
        }
    }
    #pragma unroll
    for (int oc = 0; oc < C3; ++oc) {
        float u0 = a0[oc], u1 = a1[oc], sl = s3[oc];
        a0[oc] = u0 > 0.f ? u0 : sl * u0;
        a1[oc] = u1 > 0.f ? u1 : sl * u1;
    }

    float l00 = b41[0], l01 = b41[1], l10 = b41[0], l11 = b41[1];
    #pragma unroll
    for (int c = 0; c < C3; ++c) {
        float w0 = w41[c], w1 = w41[C3 + c];
        l00 += a0[c] * w0; l01 += a0[c] * w1;
        l10 += a1[c] * w0; l11 += a1[c] * w1;
    }
    float m0 = fmaxf(l00, l01), m1 = fmaxf(l10, l11);
    float p0 = expf(l01 - m0) / (expf(l00 - m0) + expf(l01 - m0));
    float p1 = expf(l11 - m1) / (expf(l10 - m1) + expf(l11 - m1));

    float r00 = b42[0], r01 = b42[1], r02 = b42[2], r03 = b42[3];
    float r10 = b42[0], r11 = b42[1], r12 = b42[2], r13 = b42[3];
    #pragma unroll
    for (int c = 0; c < C3; ++c) {
        float w0 = w42[c], w1 = w42[C3 + c], w2 = w42[2 * C3 + c], w3v = w42[3 * C3 + c];
        r00 += a0[c] * w0; r01 += a0[c] * w1; r02 += a0[c] * w2; r03 += a0[c] * w3v;
        r10 += a1[c] * w0; r11 += a1[c] * w1; r12 += a1[c] * w2; r13 += a1[c] * w3v;
    }

    size_t n0 = (size_t)bb * N3 + (size_t)y * W3 + x0;
    scores[n0] = (p0 >= 0.6f) ? p0 : NEGV;
    regf[n0]   = make_float4(r00, r01, r02, r03);
    if (x0 + 1 < W3) {
        scores[n0 + 1] = (p1 >= 0.6f) ? p1 : NEGV;
        regf[n0 + 1]   = make_float4(r10, r11, r12, r13);
    }
}

// ------------- kernel 4: per-image NMS + box refine -------------
// Rank bound: pick k suppresses <=8 others (IoU>0.5 on this fixed 12x12/stride-2
// grid == Chebyshev-1 neighborhood), so all picks lie in the top 128+127*8=1144
// of (score desc, idx asc). Keep an exact superset (histogram cutoff, boundary
// bin INCLUDED) of the top-1152, then ONE wave runs all 128 picks from
// registers: no barriers, shfl reduction, suppression fused into the scan.
__global__ __launch_bounds__(1024) void k_nms(
        const float* __restrict__ scores, const float4* __restrict__ regf,
        float* __restrict__ outp) {
    __shared__ int   hist[2048];
    __shared__ float cs[NCAP];
    __shared__ int   cc[NCAP];
    __shared__ float psk[KP];
    __shared__ int   pck[KP];
    __shared__ int   misc[2];    // 0: compact cursor, 1: cutoff bin

    int tid = threadIdx.x;
    int bb = blockIdx.x;
    const float* sc = scores + (size_t)bb * N3;

    for (int i = tid; i < 2048; i += 1024) hist[i] = 0;
    if (tid < 2) misc[tid] = 0;
    __syncthreads();

    // pass 1: histogram of candidate scores (bin width ~2e-4 over [0.6,1])
    for (int i = tid; i < N3; i += 1024) {
        float s = sc[i];
        if (s > 0.f) {
            int b = (int)((s - 0.6f) * 5120.f);
            b = b < 0 ? 0 : (b > 2047 ? 2047 : b);
            atomicAdd(&hist[b], 1);
        }
    }
    __syncthreads();

    // wave 0: suffix-scan to find largest cutbin with suffix-count >= min(M,1152)
    if (tid < 64) {
        int part = 0;
        #pragma unroll 8
        for (int k = 0; k < 32; ++k) part += hist[tid * 32 + k];
        int suf = part;
        #pragma unroll
        for (int off = 1; off < 64; off <<= 1) {
            int o = __shfl_down(suf, off);
            suf += (tid + off < 64) ? o : 0;
        }
        int M = __shfl(suf, 0);
        int target = M < 1152 ? M : 1152;
        int base = suf - part;   // suffix count of lanes strictly above this one
        if (M > 0 && base < target && base + part >= target) {
            int acc = base, cb = tid * 32;
            for (int b = tid * 32 + 31; b >= tid * 32; --b) {
                acc += hist[b];
                if (acc >= target) { cb = b; break; }
            }
            misc[1] = cb;        // exactly one lane writes
        }
    }
    __syncthreads();
    int cutbin = misc[1];

    // pass 2: compact kept candidates (score + packed coords) into LDS
    for (int i = tid; i < N3; i += 1024) {
        float s = sc[i];
        if (s > 0.f) {
            int b = (int)((s - 0.6f) * 5120.f);
            b = b < 0 ? 0 : (b > 2047 ? 2047 : b);
            if (b >= cutbin) {
                int pos = atomicAdd(&misc[0], 1);
                if (pos < NCAP) {
                    int cy = i / W3, cx = i - cy * W3;
                    cs[pos] = s;
                    cc[pos] = (cy << 16) | cx;   // packed order == idx order
                }
            }
        }
    }
    __syncthreads();
    if (tid >= 64) return;       // single wave from here on (no more barriers)

    int K = misc[0]; if (K > NCAP) K = NCAP;
    K = __builtin_amdgcn_readfirstlane(K);
    int lane = tid;

    float sreg[24]; int cxr[24], cyr[24];
    #pragma unroll
    for (int j = 0; j < 24; ++j) {
        int e = j * 64 + lane;
        bool v = e < K;
        float s = v ? cs[e] : -INFINITY;
        int c = v ? cc[e] : 0x7FFF7FFF;
        sreg[j] = s; cxr[j] = c & 0xffff; cyr[j] = c >> 16;
    }

    int np = 0, ppx = -10000, ppy = -10000;
    for (int t = 0; t < KP; ++t) {
        float bs = -INFINITY; int bc = 0x7FFFFFFF;
        #pragma unroll
        for (int j = 0; j < 24; ++j) {
            if (j * 64 < K) {    // wave-uniform guard: dead tiles skipped
                // fused suppression vs previous pick (Chebyshev distance <= 1)
                if ((unsigned)(cxr[j] - ppx + 1) <= 2u &&
                    (unsigned)(cyr[j] - ppy + 1) <= 2u) sreg[j] = -INFINITY;
                float s = sreg[j]; int c = (cyr[j] << 16) | cxr[j];
                if (s > bs || (s == bs && c < bc)) { bs = s; bc = c; }
            }
        }
        #pragma unroll
        for (int off = 32; off; off >>= 1) {
            float os = __shfl_xor(bs, off);
            int   oc_ = __shfl_xor(bc, off);
            if (os > bs || (os == bs && oc_ < bc)) { bs = os; bc = oc_; }
        }
        if (bs < 0.f) break;     // no live candidates remain
        if (lane == 0) { psk[t] = bs; pck[t] = bc; }
        np = t + 1;
        ppx = bc & 0xffff; ppy = bc >> 16;
    }

    // epilogue: refine + write all 128 rows (zeros beyond np)
    for (int t = lane; t < KP; t += 64) {
        float* o = outp + ((size_t)bb * KP + t) * 5;
        if (t < np) {
            int c = pck[t]; float s = psk[t];
            int cx = c & 0xffff, cy = c >> 16;
            float x1 = (float)(2 * cx + 1),  y1 = (float)(2 * cy + 1);
            float x2 = (float)(2 * cx + 12), y2 = (float)(2 * cy + 12);
            float4 r = regf[(size_t)bb * N3 + (size_t)cy * W3 + cx];
            float q1 = x1 + r.x * 11.f, q2 = y1 + r.y * 11.f;   // w = h = 11
            float q3 = x2 + r.z * 11.f, q4 = y2 + r.w * 11.f;
            float rw = q3 - q1, rh = q4 - q2;
            float L = fmaxf(rw, rh);
            float nx1 = q1 + rw * 0.5f - L * 0.5f;
            float ny1 = q2 + rh * 0.5f - L * 0.5f;
            o[0] = nx1; o[1] = ny1; o[2] = nx1 + L; o[3] = ny1 + L; o[4] = s;
        } else {
            o[0] = 0.f; o[1] = 0.f; o[2] = 0.f; o[3] = 0.f; o[4] = 0.f;
        }
    }
}

// ---------------- launcher ----------------
extern "C" void kernel_launch(void* const* d_in, const int* in_sizes, int n_in,
                              void* d_out, int out_size, void* d_ws, size_t ws_size,
                              hipStream_t stream) {
    const float* im   = (const float*)d_in[0];
    const float* c1w  = (const float*)d_in[1];
    const float* c1b  = (const float*)d_in[2];
    const float* p1   = (const float*)d_in[3];
    const float* c2w  = (const float*)d_in[4];
    const float* c2b  = (const float*)d_in[5];
    const float* p2   = (const float*)d_in[6];
    const float* c3w  = (const float*)d_in[7];
    const float* c3b  = (const float*)d_in[8];
    const float* p3   = (const float*)d_in[9];
    const float* c41w = (const float*)d_in[10];
    const float* c41b = (const float*)d_in[11];
    const float* c42w = (const float*)d_in[12];
    const float* c42b = (const float*)d_in[13];

    float* ws = (float*)d_ws;
    // region0 [0 .. 7,792,800): pool1; later reused: scores (750,992) +
    //   regf (750,992..3,754,960) + w3t gap slot at 4,000,000 (4608 fl).
    // region1 [7,792,800 .. 20,030,112): conv2 output.
    const size_t POOL1_FLOATS = (size_t)BATCH * C1 * P1H * P1W;   // 7,792,800
    float*  pool1   = ws;
    float*  conv2b  = ws + POOL1_FLOATS;
    float*  scoresb = ws;
    float4* regfb   = (float4*)(ws + (size_t)BATCH * N3);         // 16B-aligned
    float*  w3t     = ws + 4000000;   // free gap in region0 once conv2 is done

    k_conv1pool<<<dim3(4, P1H, BATCH), dim3(64), 0, stream>>>(im, c1w, c1b, p1, pool1);
    k_conv2   <<<dim3(2, H2, BATCH), dim3(64), 0, stream>>>(pool1, c2w, c2b, p2, conv2b);
    k_repack  <<<dim3(18), dim3(256), 0, stream>>>(c3w, w3t);
    k_conv3heads<<<dim3(2, H3, BATCH), dim3(64), 0, stream>>>(conv2b, w3t, c3b, p3,
                                                              c41w, c41b, c42w, c42b,
                                                              scoresb, regfb);
    k_nms<<<dim3(BATCH), dim3(1024), 0, stream>>>(scoresb, regfb, (float*)d_out);
}

// Round 6
// 292.659 us; speedup vs baseline: 1.1552x; 1.0064x over previous
//
#include <hip/hip_runtime.h>
#include <math.h>

// ---------------- problem constants ----------------
#define BATCH 16
#define IH 384
#define IW 512
#define C1 10
#define P1H 191    // pooled H after conv1(382) / 2
#define P1W 255    // pooled W after conv1(510) / 2
#define P1WP 256   // padded row stride (even+aligned -> float2 loads)
#define P1PLANE (P1H * P1WP)     // 48896
#define C2 16
#define H2 189
#define W2 253
#define W2P 254    // padded row stride (even -> float2 loads)
#define C2PLANE (H2 * W2P)       // 48006
#define C3 32
#define H3 187
#define W3 251
#define N3 (H3*W3)        // 46937
#define KP 128
#define NCAP 1536         // NMS kept-candidate capacity (>= 1152 rank bound)
#define NEGV (-1e30f)

// ---- weight repack (runs first; outputs live at the tail of d_ws) ----
// conv2 w (OIHW oc-major) -> ci-major ; conv3 w -> ci-major.
__global__ void k_repack(const float* __restrict__ w2, const float* __restrict__ w3,
                         float* __restrict__ w2t, float* __restrict__ w3t) {
    int i = blockIdx.x * 256 + threadIdx.x;
    if (i < C2 * C1 * 9) {                       // 1440
        int k = i % 9, r = i / 9;
        int ci = r / C2, oc = r % C2;
        w2t[i] = w2[(oc * C1 + ci) * 9 + k];
    } else if (i < C2 * C1 * 9 + C3 * C2 * 9) {  // + 4608
        int j = i - C2 * C1 * 9;
        int k = j % 9, r = j / 9;
        int ci = r / C3, oc = r % C3;
        w3t[j] = w3[(oc * C2 + ci) * 9 + k];
    }
}

// ------------- kernel 1: conv1(3->10,3x3) + PReLU + maxpool2 -------------
// R2-proven shape: 16x16 threads, one pooled px x 10 ch per thread.
__global__ __launch_bounds__(256, 2) void k_conv1pool(
        const float* __restrict__ im, const float* __restrict__ w,
        const float* __restrict__ bia, const float* __restrict__ slope,
        float* __restrict__ outp) {
    int x = blockIdx.x * 16 + threadIdx.x;
    int y = blockIdx.y * 16 + threadIdx.y;
    int bb = blockIdx.z;
    if (x >= P1W || y >= P1H) return;

    float in[3][4][4];
    #pragma unroll
    for (int ci = 0; ci < 3; ++ci) {
        const float* p = im + (((size_t)bb * 3 + ci) * IH + 2 * y) * IW + 2 * x;
        #pragma unroll
        for (int r = 0; r < 4; ++r) {
            const float2* q = (const float2*)(p + (size_t)r * IW);  // 8B-aligned
            float2 a0 = q[0], a1 = q[1];
            in[ci][r][0] = a0.x; in[ci][r][1] = a0.y;
            in[ci][r][2] = a1.x; in[ci][r][3] = a1.y;
        }
    }
    #pragma unroll
    for (int ci = 0; ci < 3; ++ci)
        #pragma unroll
        for (int r = 0; r < 4; ++r)
            #pragma unroll
            for (int c = 0; c < 4; ++c)
                in[ci][r][c] = (in[ci][r][c] - 127.5f) * 0.0078125f;

    #pragma unroll
    for (int oc = 0; oc < C1; ++oc) {
        const float* wo = w + oc * 27;  // uniform -> scalar loads
        float bv = bia[oc], sv = slope[oc];
        float best = -INFINITY;
        #pragma unroll
        for (int py = 0; py < 2; ++py)
            #pragma unroll
            for (int px = 0; px < 2; ++px) {
                float acc = bv;
                #pragma unroll
                for (int ci = 0; ci < 3; ++ci)
                    #pragma unroll
                    for (int ky = 0; ky < 3; ++ky)
                        #pragma unroll
                        for (int kx = 0; kx < 3; ++kx)
                            acc += in[ci][py + ky][px + kx] * wo[(ci * 3 + ky) * 3 + kx];
                float v = acc > 0.f ? acc : sv * acc;   // PReLU then pool-max
                best = fmaxf(best, v);
            }
        // padded row stride; col 255 stays poison (zeroed by consumer tail)
        outp[((size_t)bb * C1 + oc) * P1PLANE + (size_t)y * P1WP + x] = best;
    }
}

// ------------- kernel 2: conv2(10->16,3x3) + PReLU -------------
// R2 shape (64x4 threads, 2 px x 16 oc); padded strides -> 6 float2 loads/ci.
__global__ __launch_bounds__(256, 2) void k_conv2(
        const float* __restrict__ inp, const float* __restrict__ w2t,
        const float* __restrict__ bia, const float* __restrict__ slope,
        float* __restrict__ outp) {
    int x0 = (blockIdx.x * 64 + threadIdx.x) * 2;
    int y  = blockIdx.y * 4 + threadIdx.y;
    int bb = blockIdx.z;
    if (x0 >= W2 || y >= H2) return;

    float a0[C2], a1[C2];
    #pragma unroll
    for (int oc = 0; oc < C2; ++oc) { a0[oc] = bia[oc]; a1[oc] = bia[oc]; }

    bool tail = (x0 + 3 > P1W - 1);   // col x0+3 == 255 is padding

    for (int ci = 0; ci < C1; ++ci) {
        const float* p = inp + ((size_t)bb * C1 + ci) * P1PLANE + (size_t)y * P1WP + x0;
        float v[3][4];
        #pragma unroll
        for (int r = 0; r < 3; ++r) {
            const float2* pr = (const float2*)(p + (size_t)r * P1WP);  // 8B-aligned
            float2 u0 = pr[0], u1 = pr[1];
            v[r][0] = u0.x; v[r][1] = u0.y; v[r][2] = u1.x;
            v[r][3] = tail ? 0.f : u1.y;
        }
        const float* wc = w2t + ci * (C2 * 9);   // ci-major: contiguous per ci
        #pragma unroll
        for (int oc = 0; oc < C2; ++oc) {
            const float* wo = wc + oc * 9;
            float s0 = a0[oc], s1 = a1[oc];
            #pragma unroll
            for (int ky = 0; ky < 3; ++ky)
                #pragma unroll
                for (int kx = 0; kx < 3; ++kx) {
                    float wv = wo[ky * 3 + kx];
                    s0 += v[ky][kx]     * wv;
                    s1 += v[ky][kx + 1] * wv;
                }
            a0[oc] = s0; a1[oc] = s1;
        }
    }
    bool px1 = (x0 + 1 < W2);
    #pragma unroll
    for (int oc = 0; oc < C2; ++oc) {
        float sl = slope[oc];
        float* o = outp + ((size_t)bb * C2 + oc) * C2PLANE + (size_t)y * W2P + x0;
        float u0 = a0[oc]; o[0] = u0 > 0.f ? u0 : sl * u0;
        if (px1) { float u1 = a1[oc]; o[1] = u1 > 0.f ? u1 : sl * u1; }
    }
}

// ------------- kernel 3: conv3(16->32,3x3)+PReLU + heads + softmax + mask ----
// R2 shape (64x4, 2 px x 32 oc, 52 VGPR); padded input stride -> 6 float2/ci.
__global__ __launch_bounds__(256, 2) void k_conv3heads(
        const float* __restrict__ inp, const float* __restrict__ w3t,
        const float* __restrict__ b3, const float* __restrict__ s3,
        const float* __restrict__ w41, const float* __restrict__ b41,
        const float* __restrict__ w42, const float* __restrict__ b42,
        float* __restrict__ scores, float4* __restrict__ regf) {
    int x0 = (blockIdx.x * 64 + threadIdx.x) * 2;
    int y  = blockIdx.y * 4 + threadIdx.y;
    int bb = blockIdx.z;
    if (x0 >= W3 || y >= H3) return;

    float a0[C3], a1[C3];
    #pragma unroll
    for (int oc = 0; oc < C3; ++oc) { a0[oc] = b3[oc]; a1[oc] = b3[oc]; }

    bool tail = (x0 + 3 > W2 - 1);   // col x0+3 == 253 is padding

    for (int ci = 0; ci < C2; ++ci) {
        const float* p = inp + ((size_t)bb * C2 + ci) * C2PLANE + (size_t)y * W2P + x0;
        float v[3][4];
        #pragma unroll
        for (int r = 0; r < 3; ++r) {
            const float2* pr = (const float2*)(p + (size_t)r * W2P);  // 8B-aligned
            float2 u0 = pr[0], u1 = pr[1];
            v[r][0] = u0.x; v[r][1] = u0.y; v[r][2] = u1.x;
            v[r][3] = tail ? 0.f : u1.y;
        }
        const float* wc = w3t + ci * (C3 * 9);   // ci-major: contiguous per ci
        #pragma unroll
        for (int oc = 0; oc < C3; ++oc) {
            const float* wo = wc + oc * 9;
            float s0 = a0[oc], s1 = a1[oc];
            #pragma unroll
            for (int ky = 0; ky < 3; ++ky)
                #pragma unroll
                for (int kx = 0; kx < 3; ++kx) {
                    float wv = wo[ky * 3 + kx];
                    s0 += v[ky][kx]     * wv;
                    s1 += v[ky][kx + 1] * wv;
                }
            a0[oc] = s0; a1[oc] = s1;
        }
    }
    #pragma unroll
    for (int oc = 0; oc < C3; ++oc) {
        float u0 = a0[oc], u1 = a1[oc], sl = s3[oc];
        a0[oc] = u0 > 0.f ? u0 : sl * u0;
        a1[oc] = u1 > 0.f ? u1 : sl * u1;
    }

    float l00 = b41[0], l01 = b41[1], l10 = b41[0], l11 = b41[1];
    #pragma unroll
    for (int c = 0; c < C3; ++c) {
        float w0 = w41[c], w1 = w41[C3 + c];
        l00 += a0[c] * w0; l01 += a0[c] * w1;
        l10 += a1[c] * w0; l11 += a1[c] * w1;
    }
    float m0 = fmaxf(l00, l01), m1 = fmaxf(l10, l11);
    float p0 = expf(l01 - m0) / (expf(l00 - m0) + expf(l01 - m0));
    float p1 = expf(l11 - m1) / (expf(l10 - m1) + expf(l11 - m1));

    float r00 = b42[0], r01 = b42[1], r02 = b42[2], r03 = b42[3];
    float r10 = b42[0], r11 = b42[1], r12 = b42[2], r13 = b42[3];
    #pragma unroll
    for (int c = 0; c < C3; ++c) {
        float w0 = w42[c], w1 = w42[C3 + c], w2 = w42[2 * C3 + c], w3v = w42[3 * C3 + c];
        r00 += a0[c] * w0; r01 += a0[c] * w1; r02 += a0[c] * w2; r03 += a0[c] * w3v;
        r10 += a1[c] * w0; r11 += a1[c] * w1; r12 += a1[c] * w2; r13 += a1[c] * w3v;
    }

    size_t n0 = (size_t)bb * N3 + (size_t)y * W3 + x0;
    scores[n0] = (p0 >= 0.6f) ? p0 : NEGV;
    regf[n0]   = make_float4(r00, r01, r02, r03);
    if (x0 + 1 < W3) {
        scores[n0 + 1] = (p1 >= 0.6f) ? p1 : NEGV;
        regf[n0 + 1]   = make_float4(r10, r11, r12, r13);
    }
}

// ------------- kernel 4: per-image NMS + box refine (R4/R5-proven) -------------
// Rank bound: each pick suppresses <=8 others (IoU>0.5 on this fixed grid ==
// Chebyshev-1 neighborhood) -> picks lie in top 128+127*8=1144 of (score desc,
// idx asc). Histogram cutoff keeps an exact superset; ONE wave runs all 128
// picks from registers (no barriers, shfl reduce, fused suppression).
__global__ __launch_bounds__(1024) void k_nms(
        const float* __restrict__ scores, const float4* __restrict__ regf,
        float* __restrict__ outp) {
    __shared__ int   hist[2048];
    __shared__ float cs[NCAP];
    __shared__ int   cc[NCAP];
    __shared__ float psk[KP];
    __shared__ int   pck[KP];
    __shared__ int   misc[2];    // 0: compact cursor, 1: cutoff bin

    int tid = threadIdx.x;
    int bb = blockIdx.x;
    const float* sc = scores + (size_t)bb * N3;

    for (int i = tid; i < 2048; i += 1024) hist[i] = 0;
    if (tid < 2) misc[tid] = 0;
    __syncthreads();

    for (int i = tid; i < N3; i += 1024) {
        float s = sc[i];
        if (s > 0.f) {
            int b = (int)((s - 0.6f) * 5120.f);
            b = b < 0 ? 0 : (b > 2047 ? 2047 : b);
            atomicAdd(&hist[b], 1);
        }
    }
    __syncthreads();

    if (tid < 64) {
        int part = 0;
        #pragma unroll 8
        for (int k = 0; k < 32; ++k) part += hist[tid * 32 + k];
        int suf = part;
        #pragma unroll
        for (int off = 1; off < 64; off <<= 1) {
            int o = __shfl_down(suf, off);
            suf += (tid + off < 64) ? o : 0;
        }
        int M = __shfl(suf, 0);
        int target = M < 1152 ? M : 1152;
        int base = suf - part;
        if (M > 0 && base < target && base + part >= target) {
            int acc = base, cb = tid * 32;
            for (int b = tid * 32 + 31; b >= tid * 32; --b) {
                acc += hist[b];
                if (acc >= target) { cb = b; break; }
            }
            misc[1] = cb;
        }
    }
    __syncthreads();
    int cutbin = misc[1];

    for (int i = tid; i < N3; i += 1024) {
        float s = sc[i];
        if (s > 0.f) {
            int b = (int)((s - 0.6f) * 5120.f);
            b = b < 0 ? 0 : (b > 2047 ? 2047 : b);
            if (b >= cutbin) {
                int pos = atomicAdd(&misc[0], 1);
                if (pos < NCAP) {
                    int cy = i / W3, cx = i - cy * W3;
                    cs[pos] = s;
                    cc[pos] = (cy << 16) | cx;
                }
            }
        }
    }
    __syncthreads();
    if (tid >= 64) return;

    int K = misc[0]; if (K > NCAP) K = NCAP;
    K = __builtin_amdgcn_readfirstlane(K);
    int lane = tid;

    float sreg[24]; int cxr[24], cyr[24];
    #pragma unroll
    for (int j = 0; j < 24; ++j) {
        int e = j * 64 + lane;
        bool v = e < K;
        float s = v ? cs[e] : -INFINITY;
        int c = v ? cc[e] : 0x7FFF7FFF;
        sreg[j] = s; cxr[j] = c & 0xffff; cyr[j] = c >> 16;
    }

    int np = 0, ppx = -10000, ppy = -10000;
    for (int t = 0; t < KP; ++t) {
        float bs = -INFINITY; int bc = 0x7FFFFFFF;
        #pragma unroll
        for (int j = 0; j < 24; ++j) {
            if (j * 64 < K) {
                if ((unsigned)(cxr[j] - ppx + 1) <= 2u &&
                    (unsigned)(cyr[j] - ppy + 1) <= 2u) sreg[j] = -INFINITY;
                float s = sreg[j]; int c = (cyr[j] << 16) | cxr[j];
                if (s > bs || (s == bs && c < bc)) { bs = s; bc = c; }
            }
        }
        #pragma unroll
        for (int off = 32; off; off >>= 1) {
            float os = __shfl_xor(bs, off);
            int   oc_ = __shfl_xor(bc, off);
            if (os > bs || (os == bs && oc_ < bc)) { bs = os; bc = oc_; }
        }
        if (bs < 0.f) break;
        if (lane == 0) { psk[t] = bs; pck[t] = bc; }
        np = t + 1;
        ppx = bc & 0xffff; ppy = bc >> 16;
    }

    for (int t = lane; t < KP; t += 64) {
        float* o = outp + ((size_t)bb * KP + t) * 5;
        if (t < np) {
            int c = pck[t]; float s = psk[t];
            int cx = c & 0xffff, cy = c >> 16;
            float x1 = (float)(2 * cx + 1),  y1 = (float)(2 * cy + 1);
            float x2 = (float)(2 * cx + 12), y2 = (float)(2 * cy + 12);
            float4 r = regf[(size_t)bb * N3 + (size_t)cy * W3 + cx];
            float q1 = x1 + r.x * 11.f, q2 = y1 + r.y * 11.f;   // w = h = 11
            float q3 = x2 + r.z * 11.f, q4 = y2 + r.w * 11.f;
            float rw = q3 - q1, rh = q4 - q2;
            float L = fmaxf(rw, rh);
            float nx1 = q1 + rw * 0.5f - L * 0.5f;
            float ny1 = q2 + rh * 0.5f - L * 0.5f;
            o[0] = nx1; o[1] = ny1; o[2] = nx1 + L; o[3] = ny1 + L; o[4] = s;
        } else {
            o[0] = 0.f; o[1] = 0.f; o[2] = 0.f; o[3] = 0.f; o[4] = 0.f;
        }
    }
}

// ---------------- launcher ----------------
extern "C" void kernel_launch(void* const* d_in, const int* in_sizes, int n_in,
                              void* d_out, int out_size, void* d_ws, size_t ws_size,
                              hipStream_t stream) {
    const float* im   = (const float*)d_in[0];
    const float* c1w  = (const float*)d_in[1];
    const float* c1b  = (const float*)d_in[2];
    const float* p1   = (const float*)d_in[3];
    const float* c2w  = (const float*)d_in[4];
    const float* c2b  = (const float*)d_in[5];
    const float* p2   = (const float*)d_in[6];
    const float* c3w  = (const float*)d_in[7];
    const float* c3b  = (const float*)d_in[8];
    const float* p3   = (const float*)d_in[9];
    const float* c41w = (const float*)d_in[10];
    const float* c41b = (const float*)d_in[11];
    const float* c42w = (const float*)d_in[12];
    const float* c42b = (const float*)d_in[13];

    float* ws = (float*)d_ws;
    // layout (floats):
    //   [0 .. 7,823,360)              pool1 (padded 256-stride); after conv2 is
    //       consumed, region reused: scores [0..750,992) + regf [750,992..3,754,960)
    //   [7,823,360 .. 20,112,896)     conv2 out (padded 254-stride)
    //   [20,112,896 .. +1440)         w2t   [.. +4608) w3t
    const size_t POOL1P = (size_t)BATCH * C1 * P1PLANE;   // 7,823,360
    const size_t CONV2P = (size_t)BATCH * C2 * C2PLANE;   // 12,289,536
    float*  pool1   = ws;
    float*  conv2b  = ws + POOL1P;
    float*  w2t     = ws + POOL1P + CONV2P;
    float*  w3t     = w2t + C2 * C1 * 9;
    float*  scoresb = ws;                                  // reuse region0
    float4* regfb   = (float4*)(ws + (size_t)BATCH * N3);  // 16B-aligned

    k_repack  <<<dim3(24), dim3(256), 0, stream>>>(c2w, c3w, w2t, w3t);
    k_conv1pool<<<dim3(16, 12, BATCH), dim3(16, 16), 0, stream>>>(im, c1w, c1b, p1, pool1);
    k_conv2   <<<dim3(2, 48, BATCH), dim3(64, 4), 0, stream>>>(pool1, w2t, c2b, p2, conv2b);
    k_conv3heads<<<dim3(2, 47, BATCH), dim3(64, 4), 0, stream>>>(conv2b, w3t, c3b, p3,
                                                                 c41w, c41b, c42w, c42b,
                                                                 scoresb, regfb);
    k_nms<<<dim3(BATCH), dim3(1024), 0, stream>>>(scoresb, regfb, (float*)d_out);
}